// Round 7
// baseline (456.931 us; speedup 1.0000x reference)
//
#include <hip/hip_runtime.h>

#define V 4096
#define H 256
#define O 512
#define B 64
#define T 512

typedef __attribute__((ext_vector_type(8))) short bf16x8;
typedef __attribute__((ext_vector_type(4))) float f32x4;
typedef __attribute__((ext_vector_type(2))) float f32x2;

__device__ __forceinline__ unsigned short f2bf(float f) {
    unsigned int u = __float_as_uint(f);
    u += 0x7fffu + ((u >> 16) & 1u);   // round-to-nearest-even
    return (unsigned short)(u >> 16);
}
__device__ __forceinline__ float bf2f(unsigned short s) {
    return __uint_as_float(((unsigned int)s) << 16);
}

// DPP quad-perm adds (pure VALU cross-lane; quads are lane-aligned)
__device__ __forceinline__ float dpp_xor1(float v) {
    int i = __float_as_int(v);
    return __int_as_float(__builtin_amdgcn_update_dpp(i, i, 0xB1, 0xf, 0xf, true)); // [1,0,3,2]
}
__device__ __forceinline__ float dpp_xor2(float v) {
    int i = __float_as_int(v);
    return __int_as_float(__builtin_amdgcn_update_dpp(i, i, 0x4E, 0xf, 0xf, true)); // [2,3,0,1]
}

// ---------------------------------------------------------------------------
// K1a: transpose W_ih [H][V] -> WihT [V][H] (coalesced per-step gather rows).
// ---------------------------------------------------------------------------
__global__ __launch_bounds__(256) void k_transpose(const float* __restrict__ Wih,
                                                   float* __restrict__ WihT) {
    __shared__ float tile[64][65];
    const int bi = blockIdx.x & 3;
    const int bv = blockIdx.x >> 2;
    const int tx = threadIdx.x & 63, ty = threadIdx.x >> 6;
#pragma unroll
    for (int s = 0; s < 16; ++s) {
        int r = ty + 4 * s;
        tile[r][tx] = Wih[(size_t)(bi * 64 + r) * V + bv * 64 + tx];
    }
    __syncthreads();
#pragma unroll
    for (int s = 0; s < 16; ++s) {
        int r = ty + 4 * s;
        WihT[(size_t)(bv * 64 + r) * H + bi * 64 + tx] = tile[tx][r];
    }
}

// ---------------------------------------------------------------------------
// K1b: split W_fc into bf16 hi + bf16 lo (B-side stays 2-term for accuracy).
// ---------------------------------------------------------------------------
__global__ __launch_bounds__(256) void k_prep(const float* __restrict__ Wfc,
                                              unsigned short* __restrict__ hi,
                                              unsigned short* __restrict__ lo) {
    int i = blockIdx.x * 256 + threadIdx.x;
    float w = Wfc[i];
    unsigned short h = f2bf(w);
    hi[i] = h;
    lo[i] = f2bf(w - bf2f(h));
}

// ---------------------------------------------------------------------------
// K2: persistent RNN. 64 blocks x 1024 threads (16 waves, 4/EU, VGPR cap 128).
// Thread (row = tid>>2, q = tid&3): owns ONE full row, k-quarter q (64 terms).
// Weights: 16 x f32x4 = 64 VGPRs — fits arch VGPRs with working set (R5/R6's
// 128-float request was AGPR-parked: VGPR_Count=88 < 128 proved it).
// Reduction: lane-quad (4r..4r+3) holds the 4 k-partials of row r ->
// xor1+xor2 DPP adds ONLY. No ds_swizzle, no selects, no row duplication.
// hs stored as SINGLE bf16 (h-quant feeds only the non-recurrent FC path,
// ~1e-4 out-error; hs_lo stream deleted -> write traffic halved).
// ---------------------------------------------------------------------------
#define CH 72   // floats per q-slice (64 data + 8 pad): q-bases hit 4 disjoint bank quads

__global__ __launch_bounds__(1024, 4) void k_rnn(
    const int* __restrict__ x, const float* __restrict__ WihT,
    const float* __restrict__ Whh, const float* __restrict__ b_ih,
    const float* __restrict__ b_hh,
    unsigned short* __restrict__ hs_hi) {
    __shared__ float hsm[2][4 * CH];
    __shared__ int xs[T];
    const int b = blockIdx.x;
    const int tid = threadIdx.x;
    const int row = tid >> 2;      // 0..255, one full row per thread
    const int q = tid & 3;         // k-quarter (64 terms)
    const int k0 = 64 * q;

    // W_hh[row][k0..k0+64) : 16 x f32x4 = 64 VGPRs
    f32x4 w4[16];
    {
        const f32x4* wr = (const f32x4*)(Whh + (size_t)row * H + k0);
#pragma unroll
        for (int j = 0; j < 16; ++j) w4[j] = wr[j];
    }
#pragma unroll
    for (int j = 0; j < 16; ++j)
        asm volatile("" : "+v"(w4[j]));   // opaque: no remat from global

    if (tid < T) xs[tid] = x[b * T + tid];
    if (tid < 4 * CH) hsm[0][tid] = 0.0f;
    const float bias = b_ih[row] + b_hh[row];
    __syncthreads();

    unsigned short* ph = hs_hi + (size_t)b * T * H + row;

    float xp_cur = WihT[(size_t)xs[0] * H + row];
    unsigned short h_prev = 0;

    for (int t = 0; t < T; ++t) {
        // store h_{t-1} (one lane per row); drains async under this step's dot
        if (t > 0 && q == 1)
            __builtin_nontemporal_store(h_prev, &ph[(size_t)(t - 1) * H]);
        int tn = (t + 1 < T) ? t + 1 : t;
        float xp_next = WihT[(size_t)xs[tn] * H + row];

        // 16 x ds_read_b128; per instr the 4 q-bases cover disjoint bank quads
        const f32x4* hv = (const f32x4*)&hsm[t & 1][q * CH];
        f32x4 a0 = {0,0,0,0}, a1 = {0,0,0,0}, a2 = {0,0,0,0}, a3 = {0,0,0,0};
#pragma unroll
        for (int j = 0; j < 16; j += 4) {
            a0 += hv[j]     * w4[j];
            a1 += hv[j + 1] * w4[j + 1];
            a2 += hv[j + 2] * w4[j + 2];
            a3 += hv[j + 3] * w4[j + 3];
        }
        f32x4 bb = (a0 + a1) + (a2 + a3);
        float s = (bb[0] + bb[1]) + (bb[2] + bb[3]);
        // quad reduce over k-quarters: 2 DPP adds, all 4 lanes get the sum
        s += dpp_xor1(s);
        s += dpp_xor2(s);

        float pre = s + xp_cur + bias;
        float e = __expf(2.0f * pre);              // tanh = 1 - 2/(e^{2x}+1)
        float hval = 1.0f - 2.0f * __builtin_amdgcn_rcpf(e + 1.0f);

        if (q == 0)
            hsm[(t + 1) & 1][(row >> 6) * CH + (row & 63)] = hval;
        h_prev = f2bf(hval);
        xp_cur = xp_next;

        // relaxed barrier: LDS visibility only; globals stay in flight
        asm volatile("s_waitcnt lgkmcnt(0)" ::: "memory");
        __builtin_amdgcn_s_barrier();
        asm volatile("" ::: "memory");
    }
    if (q == 1) ph[(size_t)(T - 1) * H] = h_prev;
}

// ---------------------------------------------------------------------------
// K3: FC GEMM [32768,256] x [256,512], A = bf16 hs, B = W_fc hi+lo (2 MFMA).
// 128x128 tile, BK=64, 4 waves (2x2, 64x64 each), XOR-swizzled LDS.
// ---------------------------------------------------------------------------
__global__ __launch_bounds__(256, 2) void k_fc(
    const unsigned short* __restrict__ hs_hi,
    const unsigned short* __restrict__ wfc_hi, const unsigned short* __restrict__ wfc_lo,
    const float* __restrict__ b_fc, float* __restrict__ out) {
    __shared__ short sA[128 * 64], sBh[128 * 64], sBl[128 * 64];
    const int tid = threadIdx.x;
    const int bm = blockIdx.x >> 2, bn = blockIdx.x & 3;
    const int m0 = bm * 128, n0 = bn * 128;
    const int w = tid >> 6, lane = tid & 63;
    const int wm = w >> 1, wn = w & 1;
    const int l16 = lane & 15, g = lane >> 4;

    f32x4 acc[4][4];
#pragma unroll
    for (int a = 0; a < 4; ++a)
#pragma unroll
        for (int cc = 0; cc < 4; ++cc)
#pragma unroll
            for (int qq = 0; qq < 4; ++qq) acc[a][cc][qq] = 0.0f;

    for (int kt = 0; kt < 4; ++kt) {
        const int k0 = kt * 64;
#pragma unroll
        for (int s = 0; s < 4; ++s) {
            int cidx = tid + 256 * s;
            int r = cidx >> 3, slot = cidx & 7;
            int dst = r * 64 + ((slot ^ (r & 7)) << 3);
            size_t ga = (size_t)(m0 + r) * 256 + k0 + slot * 8;
            *(bf16x8*)&sA[dst] = *(const bf16x8*)&hs_hi[ga];
            size_t gb = (size_t)(n0 + r) * 256 + k0 + slot * 8;
            *(bf16x8*)&sBh[dst] = *(const bf16x8*)&wfc_hi[gb];
            *(bf16x8*)&sBl[dst] = *(const bf16x8*)&wfc_lo[gb];
        }
        __syncthreads();
#pragma unroll
        for (int kc = 0; kc < 2; ++kc) {
            bf16x8 ah[4], bh[4], bl[4];
            const int slot = kc * 4 + g;
#pragma unroll
            for (int mi = 0; mi < 4; ++mi) {
                int r = wm * 64 + mi * 16 + l16;
                int off = r * 64 + ((slot ^ (r & 7)) << 3);
                ah[mi] = *(const bf16x8*)&sA[off];
            }
#pragma unroll
            for (int ni = 0; ni < 4; ++ni) {
                int r = wn * 64 + ni * 16 + l16;
                int off = r * 64 + ((slot ^ (r & 7)) << 3);
                bh[ni] = *(const bf16x8*)&sBh[off];
                bl[ni] = *(const bf16x8*)&sBl[off];
            }
#pragma unroll
            for (int mi = 0; mi < 4; ++mi)
#pragma unroll
                for (int ni = 0; ni < 4; ++ni) {
                    acc[mi][ni] = __builtin_amdgcn_mfma_f32_16x16x32_bf16(
                        ah[mi], bh[ni], acc[mi][ni], 0, 0, 0);
                    acc[mi][ni] = __builtin_amdgcn_mfma_f32_16x16x32_bf16(
                        ah[mi], bl[ni], acc[mi][ni], 0, 0, 0);
                }
        }
        __syncthreads();
    }
#pragma unroll
    for (int ni = 0; ni < 4; ++ni) {
        int n = n0 + wn * 64 + ni * 16 + l16;
        float bfc = b_fc[n];
#pragma unroll
        for (int mi = 0; mi < 4; ++mi) {
#pragma unroll
            for (int qq = 0; qq < 4; ++qq) {
                int m = m0 + wm * 64 + mi * 16 + g * 4 + qq;
                out[(size_t)m * O + n] = acc[mi][ni][qq] + bfc;
            }
        }
    }
}

extern "C" void kernel_launch(void* const* d_in, const int* in_sizes, int n_in,
                              void* d_out, int out_size, void* d_ws, size_t ws_size,
                              hipStream_t stream) {
    (void)in_sizes; (void)n_in; (void)out_size; (void)ws_size;
    const int*   x    = (const int*)d_in[0];
    const float* Wih  = (const float*)d_in[1];
    const float* Whh  = (const float*)d_in[2];
    const float* bih  = (const float*)d_in[3];
    const float* bhh  = (const float*)d_in[4];
    const float* Wfc  = (const float*)d_in[5];
    const float* bfc  = (const float*)d_in[6];
    float* out = (float*)d_out;

    char* ws = (char*)d_ws;
    float*          WihT = (float*)ws;                                  // 4 MB
    unsigned short* wfch = (unsigned short*)(ws + 4194304);             // 256 KB
    unsigned short* wfcl = (unsigned short*)(ws + 4194304 + 262144);    // 256 KB
    unsigned short* hsh  = (unsigned short*)(ws + 4718592);             // 16 MB

    k_transpose<<<256, 256, 0, stream>>>(Wih, WihT);
    k_prep<<<512, 256, 0, stream>>>(Wfc, wfch, wfcl);
    k_rnn<<<64, 1024, 0, stream>>>(x, WihT, Whh, bih, bhh, hsh);
    k_fc<<<1024, 256, 0, stream>>>(hsh, wfch, wfcl, bfc, out);
}

// Round 8
// 345.593 us; speedup vs baseline: 1.3222x; 1.3222x over previous
//
#include <hip/hip_runtime.h>

#define V 4096
#define H 256
#define O 512
#define B 64
#define T 512

typedef __attribute__((ext_vector_type(8))) short bf16x8;
typedef __attribute__((ext_vector_type(4))) float f32x4;
typedef __attribute__((ext_vector_type(2))) float f32x2;

__device__ __forceinline__ unsigned short f2bf(float f) {
    unsigned int u = __float_as_uint(f);
    u += 0x7fffu + ((u >> 16) & 1u);   // round-to-nearest-even
    return (unsigned short)(u >> 16);
}
__device__ __forceinline__ float bf2f(unsigned short s) {
    return __uint_as_float(((unsigned int)s) << 16);
}

// DPP cross-lane adds (VALU pipe, zero DS cost)
__device__ __forceinline__ float dpp_xor1(float v) {
    int i = __float_as_int(v);
    return __int_as_float(__builtin_amdgcn_update_dpp(i, i, 0xB1, 0xf, 0xf, true)); // quad_perm[1,0,3,2]
}
__device__ __forceinline__ float dpp_xor2(float v) {
    int i = __float_as_int(v);
    return __int_as_float(__builtin_amdgcn_update_dpp(i, i, 0x4E, 0xf, 0xf, true)); // quad_perm[2,3,0,1]
}
__device__ __forceinline__ float dpp_ror8(float v) {
    // row_ror:8 — within each 16-lane row, lane c reads lane c^8
    int i = __float_as_int(v);
    return __int_as_float(__builtin_amdgcn_update_dpp(i, i, 0x128, 0xf, 0xf, true));
}

// ---------------------------------------------------------------------------
// K1a: transpose W_ih [H][V] -> WihT [V][H] (coalesced per-step gather rows).
// ---------------------------------------------------------------------------
__global__ __launch_bounds__(256) void k_transpose(const float* __restrict__ Wih,
                                                   float* __restrict__ WihT) {
    __shared__ float tile[64][65];
    const int bi = blockIdx.x & 3;
    const int bv = blockIdx.x >> 2;
    const int tx = threadIdx.x & 63, ty = threadIdx.x >> 6;
#pragma unroll
    for (int s = 0; s < 16; ++s) {
        int r = ty + 4 * s;
        tile[r][tx] = Wih[(size_t)(bi * 64 + r) * V + bv * 64 + tx];
    }
    __syncthreads();
#pragma unroll
    for (int s = 0; s < 16; ++s) {
        int r = ty + 4 * s;
        WihT[(size_t)(bv * 64 + r) * H + bi * 64 + tx] = tile[tx][r];
    }
}

// ---------------------------------------------------------------------------
// K1b: split W_fc into bf16 hi + bf16 lo (B-side stays 2-term for accuracy).
// ---------------------------------------------------------------------------
__global__ __launch_bounds__(256) void k_prep(const float* __restrict__ Wfc,
                                              unsigned short* __restrict__ hi,
                                              unsigned short* __restrict__ lo) {
    int i = blockIdx.x * 256 + threadIdx.x;
    float w = Wfc[i];
    unsigned short h = f2bf(w);
    hi[i] = h;
    lo[i] = f2bf(w - bf2f(h));
}

// ---------------------------------------------------------------------------
// K2: persistent RNN (R5 structure, AGPR fix). 64 blocks x 512 threads,
// __launch_bounds__(512,2) -> 256-VGPR cap, 2 waves/EU.
// Thread (g = tid>>4, c = tid&15): rows 8g..8g+7, k-16th c (16 terms).
// KEY FIX vs R5: weights re-pinned in arch VGPRs EVERY iteration (empty asm,
// zero instructions) — defeats AGPR-parking, which was costing one
// v_accvgpr_read per weight-use per step (~500 cyc/SIMD; VGPR_Count=88 with
// no memory traffic was the tell). hs stored as single bf16 (R7-verified).
// ---------------------------------------------------------------------------
#define CH16 20   // chunk stride in floats (16 data + 4 pad)

__global__ __launch_bounds__(512, 2) void k_rnn(
    const int* __restrict__ x, const float* __restrict__ WihT,
    const float* __restrict__ Whh, const float* __restrict__ b_ih,
    const float* __restrict__ b_hh,
    unsigned short* __restrict__ hs_hi) {
    __shared__ float hsm[2][16 * CH16];
    __shared__ int xs[T];
    const int b = blockIdx.x;
    const int tid = threadIdx.x;
    const int g = tid >> 4;        // row-group 0..31 (8 rows each)
    const int c = tid & 15;        // k-16th 0..15 (16 terms)
    const int cr = c & 7;          // row within group this lane finalizes
    const int row = 8 * g + cr;
    const int k0 = 16 * c;

    // W_hh rows 8g..8g+7, k in [k0, k0+16): 64 f32x2 = 128 VGPRs
    f32x2 w2[8][8];
#pragma unroll
    for (int r = 0; r < 8; ++r) {
        const f32x2* wr = (const f32x2*)(Whh + (size_t)(8 * g + r) * H + k0);
#pragma unroll
        for (int q = 0; q < 8; ++q) w2[r][q] = wr[q];
    }
#pragma unroll
    for (int r = 0; r < 8; ++r)
#pragma unroll
        for (int q = 0; q < 8; ++q)
            asm volatile("" : "+v"(w2[r][q]));

    xs[tid] = x[b * T + tid];
    if (tid < 16 * CH16) hsm[0][tid] = 0.0f;
    const float bias = b_ih[row] + b_hh[row];
    __syncthreads();

    unsigned short* ph = hs_hi + (size_t)b * T * H + row;

    float xp_cur = WihT[(size_t)xs[0] * H + row];
    unsigned short h_prev = 0;

    for (int t = 0; t < T; ++t) {
        // store h_{t-1} (lanes c<8, one per row); drains async under the dot
        if (t > 0 && c < 8)
            __builtin_nontemporal_store(h_prev, &ph[(size_t)(t - 1) * H]);
        int tn = (t + 1 < T) ? t + 1 : t;
        float xp_next = WihT[(size_t)xs[tn] * H + row];

        // 4 x ds_read_b128: this lane's 16-float h-slice
        const f32x4* hv = (const f32x4*)&hsm[t & 1][c * CH16];
        f32x4 q0 = hv[0], q1 = hv[1], q2 = hv[2], q3 = hv[3];
        f32x2 h2[8] = {{q0[0], q0[1]}, {q0[2], q0[3]}, {q1[0], q1[1]}, {q1[2], q1[3]},
                       {q2[0], q2[1]}, {q2[2], q2[3]}, {q3[0], q3[1]}, {q3[2], q3[3]}};
        f32x2 a0 = {0,0}, a1 = {0,0}, a2 = {0,0}, a3 = {0,0};
        f32x2 a4 = {0,0}, a5 = {0,0}, a6 = {0,0}, a7 = {0,0};
#pragma unroll
        for (int q = 0; q < 8; ++q) {
            a0 += h2[q] * w2[0][q];
            a1 += h2[q] * w2[1][q];
            a2 += h2[q] * w2[2][q];
            a3 += h2[q] * w2[3][q];
            a4 += h2[q] * w2[4][q];
            a5 += h2[q] * w2[5][q];
            a6 += h2[q] * w2[6][q];
            a7 += h2[q] * w2[7][q];
        }
        float s0 = a0[0] + a0[1], s1 = a1[0] + a1[1];
        float s2 = a2[0] + a2[1], s3 = a3[0] + a3[1];
        float s4 = a4[0] + a4[1], s5 = a5[0] + a5[1];
        float s6 = a6[0] + a6[1], s7 = a7[0] + a7[1];
        // level 1 (k): DPP adds; keep rows with r&1 == c&1
        s0 += dpp_xor1(s0); s1 += dpp_xor1(s1); s2 += dpp_xor1(s2); s3 += dpp_xor1(s3);
        s4 += dpp_xor1(s4); s5 += dpp_xor1(s5); s6 += dpp_xor1(s6); s7 += dpp_xor1(s7);
        const bool b0 = c & 1, b1 = c & 2, b2 = c & 4;
        float u0 = b0 ? s1 : s0;
        float u1 = b0 ? s3 : s2;
        float u2 = b0 ? s5 : s4;
        float u3 = b0 ? s7 : s6;
        // level 2: DPP adds; keep rows with r&2 == c&2
        u0 += dpp_xor2(u0); u1 += dpp_xor2(u1); u2 += dpp_xor2(u2); u3 += dpp_xor2(u3);
        float v0 = b1 ? u1 : u0;
        float v1 = b1 ? u3 : u2;
        // level 4: ds_swizzle xor4 (2 DS ops); keep row with r&4 == c&4
        v0 += __int_as_float(__builtin_amdgcn_ds_swizzle(__float_as_int(v0), 0x101F));
        v1 += __int_as_float(__builtin_amdgcn_ds_swizzle(__float_as_int(v1), 0x101F));
        float own = b2 ? v1 : v0;      // row = c&7, k-half per bit3 of c
        // level 8: DPP row_ror:8 == xor8 within the 16-lane group (VALU)
        own += dpp_ror8(own);

        float pre = own + xp_cur + bias;
        float e = __expf(2.0f * pre);              // tanh = 1 - 2/(e^{2x}+1)
        float hval = 1.0f - 2.0f * __builtin_amdgcn_rcpf(e + 1.0f);

        if (c < 8)
            hsm[(t + 1) & 1][(row >> 4) * CH16 + (row & 15)] = hval;
        h_prev = f2bf(hval);
        xp_cur = xp_next;

        // re-pin weights: forces arch-VGPR residency across the backedge
        // (zero instructions; AGPR-parking would now need a write+read/step)
#pragma unroll
        for (int r = 0; r < 8; ++r)
#pragma unroll
            for (int q = 0; q < 8; ++q)
                asm volatile("" : "+v"(w2[r][q]));

        // relaxed barrier: LDS visibility only; globals stay in flight
        asm volatile("s_waitcnt lgkmcnt(0)" ::: "memory");
        __builtin_amdgcn_s_barrier();
        asm volatile("" ::: "memory");
    }
    if (c < 8) ph[(size_t)(T - 1) * H] = h_prev;
}

// ---------------------------------------------------------------------------
// K3: FC GEMM [32768,256] x [256,512], A = bf16 hs, B = W_fc hi+lo (2 MFMA).
// 128x128 tile, BK=64, 4 waves (2x2, 64x64 each), XOR-swizzled LDS.
// ---------------------------------------------------------------------------
__global__ __launch_bounds__(256, 2) void k_fc(
    const unsigned short* __restrict__ hs_hi,
    const unsigned short* __restrict__ wfc_hi, const unsigned short* __restrict__ wfc_lo,
    const float* __restrict__ b_fc, float* __restrict__ out) {
    __shared__ short sA[128 * 64], sBh[128 * 64], sBl[128 * 64];
    const int tid = threadIdx.x;
    const int bm = blockIdx.x >> 2, bn = blockIdx.x & 3;
    const int m0 = bm * 128, n0 = bn * 128;
    const int w = tid >> 6, lane = tid & 63;
    const int wm = w >> 1, wn = w & 1;
    const int l16 = lane & 15, g = lane >> 4;

    f32x4 acc[4][4];
#pragma unroll
    for (int a = 0; a < 4; ++a)
#pragma unroll
        for (int cc = 0; cc < 4; ++cc)
#pragma unroll
            for (int qq = 0; qq < 4; ++qq) acc[a][cc][qq] = 0.0f;

    for (int kt = 0; kt < 4; ++kt) {
        const int k0 = kt * 64;
#pragma unroll
        for (int s = 0; s < 4; ++s) {
            int cidx = tid + 256 * s;
            int r = cidx >> 3, slot = cidx & 7;
            int dst = r * 64 + ((slot ^ (r & 7)) << 3);
            size_t ga = (size_t)(m0 + r) * 256 + k0 + slot * 8;
            *(bf16x8*)&sA[dst] = *(const bf16x8*)&hs_hi[ga];
            size_t gb = (size_t)(n0 + r) * 256 + k0 + slot * 8;
            *(bf16x8*)&sBh[dst] = *(const bf16x8*)&wfc_hi[gb];
            *(bf16x8*)&sBl[dst] = *(const bf16x8*)&wfc_lo[gb];
        }
        __syncthreads();
#pragma unroll
        for (int kc = 0; kc < 2; ++kc) {
            bf16x8 ah[4], bh[4], bl[4];
            const int slot = kc * 4 + g;
#pragma unroll
            for (int mi = 0; mi < 4; ++mi) {
                int r = wm * 64 + mi * 16 + l16;
                int off = r * 64 + ((slot ^ (r & 7)) << 3);
                ah[mi] = *(const bf16x8*)&sA[off];
            }
#pragma unroll
            for (int ni = 0; ni < 4; ++ni) {
                int r = wn * 64 + ni * 16 + l16;
                int off = r * 64 + ((slot ^ (r & 7)) << 3);
                bh[ni] = *(const bf16x8*)&sBh[off];
                bl[ni] = *(const bf16x8*)&sBl[off];
            }
#pragma unroll
            for (int mi = 0; mi < 4; ++mi)
#pragma unroll
                for (int ni = 0; ni < 4; ++ni) {
                    acc[mi][ni] = __builtin_amdgcn_mfma_f32_16x16x32_bf16(
                        ah[mi], bh[ni], acc[mi][ni], 0, 0, 0);
                    acc[mi][ni] = __builtin_amdgcn_mfma_f32_16x16x32_bf16(
                        ah[mi], bl[ni], acc[mi][ni], 0, 0, 0);
                }
        }
        __syncthreads();
    }
#pragma unroll
    for (int ni = 0; ni < 4; ++ni) {
        int n = n0 + wn * 64 + ni * 16 + l16;
        float bfc = b_fc[n];
#pragma unroll
        for (int mi = 0; mi < 4; ++mi) {
#pragma unroll
            for (int qq = 0; qq < 4; ++qq) {
                int m = m0 + wm * 64 + mi * 16 + g * 4 + qq;
                out[(size_t)m * O + n] = acc[mi][ni][qq] + bfc;
            }
        }
    }
}

extern "C" void kernel_launch(void* const* d_in, const int* in_sizes, int n_in,
                              void* d_out, int out_size, void* d_ws, size_t ws_size,
                              hipStream_t stream) {
    (void)in_sizes; (void)n_in; (void)out_size; (void)ws_size;
    const int*   x    = (const int*)d_in[0];
    const float* Wih  = (const float*)d_in[1];
    const float* Whh  = (const float*)d_in[2];
    const float* bih  = (const float*)d_in[3];
    const float* bhh  = (const float*)d_in[4];
    const float* Wfc  = (const float*)d_in[5];
    const float* bfc  = (const float*)d_in[6];
    float* out = (float*)d_out;

    char* ws = (char*)d_ws;
    float*          WihT = (float*)ws;                                  // 4 MB
    unsigned short* wfch = (unsigned short*)(ws + 4194304);             // 256 KB
    unsigned short* wfcl = (unsigned short*)(ws + 4194304 + 262144);    // 256 KB
    unsigned short* hsh  = (unsigned short*)(ws + 4718592);             // 16 MB

    k_transpose<<<256, 256, 0, stream>>>(Wih, WihT);
    k_prep<<<512, 256, 0, stream>>>(Wfc, wfch, wfcl);
    k_rnn<<<64, 512, 0, stream>>>(x, WihT, Whh, bih, bhh, hsh);
    k_fc<<<1024, 256, 0, stream>>>(hsh, wfch, wfcl, bfc, out);
}